// Round 7
// baseline (190.731 us; speedup 1.0000x reference)
//
#include <hip/hip_runtime.h>
#include <hip/hip_bf16.h>

#define C 1000
#define D 128
#define PAD 16            // one atomic target per 64B line

__device__ __forceinline__ void atomAddF(float* p, float v) { unsafeAtomicAdd(p, v); }

// Phase 1: histogram of target classes (LDS u32 atomics -> native ds_add).
__global__ __launch_bounds__(1024)
void k_hist(const int* __restrict__ tgt, unsigned* __restrict__ counts, int N) {
    __shared__ unsigned lh[C];
    const int t = threadIdx.x;
    if (t < C) lh[t] = 0u;
    __syncthreads();
    for (int i = blockIdx.x * 1024 + t; i < N; i += gridDim.x * 1024)
        atomicAdd(&lh[tgt[i]], 1u);
    __syncthreads();
    if (t < C) atomicAdd(&counts[t * PAD], lh[t]);
}

// Phase 2: exclusive scan over 1000 counts -> offsets + scatter cursors.
__global__ __launch_bounds__(1024)
void k_scan(const unsigned* __restrict__ counts, int* __restrict__ off,
            int* __restrict__ cursor) {
    __shared__ unsigned a[1024];
    const int t = threadIdx.x;
    const unsigned mine = (t < C) ? counts[t * PAD] : 0u;
    a[t] = mine;
    for (int o = 1; o < 1024; o <<= 1) {
        __syncthreads();
        const unsigned v = (t >= o) ? a[t - o] : 0u;
        __syncthreads();
        a[t] += v;
    }
    __syncthreads();
    if (t < C) {
        const unsigned excl = a[t] - mine;
        off[t] = (int)excl;
        cursor[t * PAD] = (int)excl;
    }
}

// Phase 3: scatter row indices into class-grouped order[].
__global__ __launch_bounds__(256)
void k_scatter(const int* __restrict__ tgt, int* __restrict__ cursor,
               int* __restrict__ order, int N) {
    const int i = blockIdx.x * 256 + threadIdx.x;
    if (i >= N) return;
    const int c = tgt[i];
    const int pos = atomicAdd(&cursor[c * PAD], 1);
    order[pos] = i;
}

// Phase 4: per-class sums -> means (global, L2/LLC-resident for phase 5).
// One block per class, 8 waves, half-wave = one 512B row, 4 rows in flight.
__global__ __launch_bounds__(512)
void k_sums(const float* __restrict__ emb, const int* __restrict__ order,
            const int* __restrict__ off, const unsigned* __restrict__ counts,
            float* __restrict__ means) {
    __shared__ float part[8][D];
    const int c    = blockIdx.x;
    const int t    = threadIdx.x;
    const int w    = t >> 6;
    const int lane = t & 63;
    const int half = lane >> 5;
    const int sub  = lane & 31;
    const int start = off[c];
    const int cnt   = (int)counts[c * PAD];

    const int chunk = (cnt + 7) >> 3;
    const int wsrt  = start + w * chunk;
    const int wend  = min(start + cnt, wsrt + chunk);
    float ax = 0.f, ay = 0.f, az = 0.f, aw = 0.f;
    int pos = wsrt + half;
    for (; pos + 6 < wend; pos += 8) {              // 4 rows in flight / half-wave
        const int r0 = order[pos];
        const int r1 = order[pos + 2];
        const int r2 = order[pos + 4];
        const int r3 = order[pos + 6];
        const float4 v0 = *reinterpret_cast<const float4*>(emb + (size_t)r0 * D + sub * 4);
        const float4 v1 = *reinterpret_cast<const float4*>(emb + (size_t)r1 * D + sub * 4);
        const float4 v2 = *reinterpret_cast<const float4*>(emb + (size_t)r2 * D + sub * 4);
        const float4 v3 = *reinterpret_cast<const float4*>(emb + (size_t)r3 * D + sub * 4);
        ax += v0.x + v1.x + v2.x + v3.x;
        ay += v0.y + v1.y + v2.y + v3.y;
        az += v0.z + v1.z + v2.z + v3.z;
        aw += v0.w + v1.w + v2.w + v3.w;
    }
    for (; pos < wend; pos += 2) {
        const int r0 = order[pos];
        const float4 v0 = *reinterpret_cast<const float4*>(emb + (size_t)r0 * D + sub * 4);
        ax += v0.x; ay += v0.y; az += v0.z; aw += v0.w;
    }
    ax += __shfl_xor(ax, 32);
    ay += __shfl_xor(ay, 32);
    az += __shfl_xor(az, 32);
    aw += __shfl_xor(aw, 32);
    if (half == 0) {
        part[w][sub * 4 + 0] = ax;
        part[w][sub * 4 + 1] = ay;
        part[w][sub * 4 + 2] = az;
        part[w][sub * 4 + 3] = aw;
    }
    __syncthreads();
    if (t < D) {
        float s = 0.f;
        #pragma unroll
        for (int k = 0; k < 8; ++k) s += part[k][t];
        means[c * D + t] = s / fmaxf((float)cnt, 1.f);
    }
}

// Phase 5: linear-streaming norms. Thread-per-row, no indirection, no shuffles.
// means reads are L2/LLC-hot (512 KB); one global f32 atomic per row.
__global__ __launch_bounds__(256)
void k_norms_lin(const float* __restrict__ emb, const int* __restrict__ tgt,
                 const float* __restrict__ means, float* __restrict__ normsums, int N) {
    const int i = blockIdx.x * 256 + threadIdx.x;
    if (i >= N) return;
    const int c = tgt[i];
    const float4* er = reinterpret_cast<const float4*>(emb + (size_t)i * D);
    const float4* mr = reinterpret_cast<const float4*>(means + (size_t)c * D);
    float ax = 0.f, ay = 0.f, az = 0.f, aw = 0.f;
    #pragma unroll 8
    for (int j = 0; j < D / 4; ++j) {
        const float4 v = er[j];
        const float4 m = mr[j];
        const float dx = v.x - m.x, dy = v.y - m.y, dz = v.z - m.z, dw = v.w - m.w;
        ax += dx * dx; ay += dy * dy; az += dz * dz; aw += dw * dw;
    }
    atomAddF(&normsums[c * PAD], sqrtf(ax + ay + az + aw));
}

// Phase 6: final scalar = sum_c (count>0 ? normsum/count : 0).
__global__ __launch_bounds__(256)
void k_final(const unsigned* __restrict__ counts, const float* __restrict__ normsums,
             float* __restrict__ out) {
    __shared__ float red[256];
    float acc = 0.f;
    for (int c = threadIdx.x; c < C; c += 256) {
        const unsigned cnt = counts[c * PAD];
        if (cnt > 0u) acc += normsums[c * PAD] / (float)cnt;
    }
    red[threadIdx.x] = acc;
    __syncthreads();
    for (int s = 128; s > 0; s >>= 1) {
        if (threadIdx.x < s) red[threadIdx.x] += red[threadIdx.x + s];
        __syncthreads();
    }
    if (threadIdx.x == 0) out[0] = red[0];
}

extern "C" void kernel_launch(void* const* d_in, const int* in_sizes, int n_in,
                              void* d_out, int out_size, void* d_ws, size_t ws_size,
                              hipStream_t stream) {
    const float* emb = (const float*)d_in[0];
    const int*   tgt = (const int*)d_in[1];
    const int N = in_sizes[1];

    char* ws = (char*)d_ws;
    unsigned* counts   = (unsigned*)(ws);            // C*PAD u32 (zeroed)
    float*    normsums = (float*)(ws + 65536);       // C*PAD f32 (zeroed)
    int*      off      = (int*)(ws + 131072);        // C ints
    int*      cursor   = (int*)(ws + 139264);        // C*PAD ints
    float*    means    = (float*)(ws + 204800);      // C*D f32 = 512000 B
    int*      order    = (int*)(ws + 720896);        // N ints = 2 MB

    hipMemsetAsync(d_ws, 0, 131072, stream);         // counts + normsums

    k_hist<<<256, 1024, 0, stream>>>(tgt, counts, N);
    k_scan<<<1, 1024, 0, stream>>>(counts, off, cursor);
    k_scatter<<<(N + 255) / 256, 256, 0, stream>>>(tgt, cursor, order, N);
    k_sums<<<C, 512, 0, stream>>>(emb, order, off, counts, means);
    k_norms_lin<<<(N + 255) / 256, 256, 0, stream>>>(emb, tgt, means, normsums, N);
    k_final<<<1, 256, 0, stream>>>(counts, normsums, (float*)d_out);
}

// Round 8
// 150.992 us; speedup vs baseline: 1.2632x; 1.2632x over previous
//
#include <hip/hip_runtime.h>
#include <hip/hip_bf16.h>

#define C 1000
#define D 128
#define PAD 16            // one atomic target per 64B line
#define CHUNK 64          // rows staged in LDS per pass-B iteration

__device__ __forceinline__ void atomAddF(float* p, float v) { unsafeAtomicAdd(p, v); }

// Phase 1: histogram of target classes (LDS u32 atomics -> native ds_add).
__global__ __launch_bounds__(1024)
void k_hist(const int* __restrict__ tgt, unsigned* __restrict__ counts, int N) {
    __shared__ unsigned lh[C];
    const int t = threadIdx.x;
    if (t < C) lh[t] = 0u;
    __syncthreads();
    for (int i = blockIdx.x * 1024 + t; i < N; i += gridDim.x * 1024)
        atomicAdd(&lh[tgt[i]], 1u);
    __syncthreads();
    if (t < C) atomicAdd(&counts[t * PAD], lh[t]);
}

// Phase 2: exclusive scan over 1000 counts -> offsets + scatter cursors.
__global__ __launch_bounds__(1024)
void k_scan(const unsigned* __restrict__ counts, int* __restrict__ off,
            int* __restrict__ cursor) {
    __shared__ unsigned a[1024];
    const int t = threadIdx.x;
    const unsigned mine = (t < C) ? counts[t * PAD] : 0u;
    a[t] = mine;
    for (int o = 1; o < 1024; o <<= 1) {
        __syncthreads();
        const unsigned v = (t >= o) ? a[t - o] : 0u;
        __syncthreads();
        a[t] += v;
    }
    __syncthreads();
    if (t < C) {
        const unsigned excl = a[t] - mine;
        off[t] = (int)excl;
        cursor[t * PAD] = (int)excl;
    }
}

// Phase 3: scatter row indices into class-grouped order[].
__global__ __launch_bounds__(256)
void k_scatter(const int* __restrict__ tgt, int* __restrict__ cursor,
               int* __restrict__ order, int N) {
    const int i = blockIdx.x * 256 + threadIdx.x;
    if (i >= N) return;
    const int c = tgt[i];
    const int pos = atomicAdd(&cursor[c * PAD], 1);
    order[pos] = i;
}

// Phase 4 (fused): one block per class.
//   A: sum rows (half-wave = one 512B row, 8 rows in flight) -> mean in LDS.
//   B: chunked LDS staging (64 rows, XOR-swizzled float4 groups) ->
//      8 threads/row compute norm from LDS vs in-register mean slice;
//      3 shfls/row, off the global-load critical path.
__global__ __launch_bounds__(512)
void k_fused(const float* __restrict__ emb, const int* __restrict__ order,
             const int* __restrict__ off, const unsigned* __restrict__ counts,
             float* __restrict__ percls) {
    __shared__ float part[8][D];        //  4 KB (pass A fold)
    __shared__ float mean_l[D];         //  0.5 KB
    __shared__ float stage[CHUNK * D];  // 32 KB (pass B row staging)
    __shared__ float nacc[8];
    const int c    = blockIdx.x;
    const int t    = threadIdx.x;
    const int w    = t >> 6;            // wave 0..7
    const int lane = t & 63;
    const int half = lane >> 5;
    const int sub  = lane & 31;         // float4 column group 0..31
    const int hw   = t >> 5;            // half-wave 0..15
    const int start = off[c];
    const int cnt   = (int)counts[c * PAD];

    // ---- pass A: class sum, 8 rows in flight per half-wave ----
    const int chunkA = (cnt + 7) >> 3;
    const int wsrt   = start + w * chunkA;
    const int wend   = min(start + cnt, wsrt + chunkA);
    float ax = 0.f, ay = 0.f, az = 0.f, aw = 0.f;
    int pos = wsrt + half;
    for (; pos + 14 < wend; pos += 16) {
        const int r0 = order[pos];      const int r1 = order[pos + 2];
        const int r2 = order[pos + 4];  const int r3 = order[pos + 6];
        const int r4 = order[pos + 8];  const int r5 = order[pos + 10];
        const int r6 = order[pos + 12]; const int r7 = order[pos + 14];
        const float4 v0 = *reinterpret_cast<const float4*>(emb + (size_t)r0 * D + sub * 4);
        const float4 v1 = *reinterpret_cast<const float4*>(emb + (size_t)r1 * D + sub * 4);
        const float4 v2 = *reinterpret_cast<const float4*>(emb + (size_t)r2 * D + sub * 4);
        const float4 v3 = *reinterpret_cast<const float4*>(emb + (size_t)r3 * D + sub * 4);
        const float4 v4 = *reinterpret_cast<const float4*>(emb + (size_t)r4 * D + sub * 4);
        const float4 v5 = *reinterpret_cast<const float4*>(emb + (size_t)r5 * D + sub * 4);
        const float4 v6 = *reinterpret_cast<const float4*>(emb + (size_t)r6 * D + sub * 4);
        const float4 v7 = *reinterpret_cast<const float4*>(emb + (size_t)r7 * D + sub * 4);
        ax += (v0.x + v1.x) + (v2.x + v3.x) + (v4.x + v5.x) + (v6.x + v7.x);
        ay += (v0.y + v1.y) + (v2.y + v3.y) + (v4.y + v5.y) + (v6.y + v7.y);
        az += (v0.z + v1.z) + (v2.z + v3.z) + (v4.z + v5.z) + (v6.z + v7.z);
        aw += (v0.w + v1.w) + (v2.w + v3.w) + (v4.w + v5.w) + (v6.w + v7.w);
    }
    for (; pos < wend; pos += 2) {
        const int r0 = order[pos];
        const float4 v0 = *reinterpret_cast<const float4*>(emb + (size_t)r0 * D + sub * 4);
        ax += v0.x; ay += v0.y; az += v0.z; aw += v0.w;
    }
    ax += __shfl_xor(ax, 32);
    ay += __shfl_xor(ay, 32);
    az += __shfl_xor(az, 32);
    aw += __shfl_xor(aw, 32);
    if (half == 0) {
        part[w][sub * 4 + 0] = ax;
        part[w][sub * 4 + 1] = ay;
        part[w][sub * 4 + 2] = az;
        part[w][sub * 4 + 3] = aw;
    }
    __syncthreads();
    if (t < D) {
        float s = 0.f;
        #pragma unroll
        for (int k = 0; k < 8; ++k) s += part[k][t];
        mean_l[t] = s / fmaxf((float)cnt, 1.f);
    }
    __syncthreads();

    // ---- pass B: chunked LDS staging + 8-threads-per-row norms ----
    const int sub8 = t & 7;             // slot within row group
    const int rloc = t >> 3;            // local row this thread computes (0..63)
    const float4 m0 = *reinterpret_cast<const float4*>(mean_l + (sub8 * 4 + 0) * 4);
    const float4 m1 = *reinterpret_cast<const float4*>(mean_l + (sub8 * 4 + 1) * 4);
    const float4 m2 = *reinterpret_cast<const float4*>(mean_l + (sub8 * 4 + 2) * 4);
    const float4 m3 = *reinterpret_cast<const float4*>(mean_l + (sub8 * 4 + 3) * 4);
    float local = 0.f;

    for (int cb = 0; cb < cnt; cb += CHUNK) {
        const int rem = min(CHUNK, cnt - cb);
        // stage: half-wave hw loads rows lr..lr+3 coalesced, writes swizzled
        {
            const int lr = hw * 4;
            const int q  = start + cb + lr;
            float4 s0, s1, s2, s3;
            if (lr + 0 < rem) s0 = *reinterpret_cast<const float4*>(emb + (size_t)order[q + 0] * D + sub * 4);
            if (lr + 1 < rem) s1 = *reinterpret_cast<const float4*>(emb + (size_t)order[q + 1] * D + sub * 4);
            if (lr + 2 < rem) s2 = *reinterpret_cast<const float4*>(emb + (size_t)order[q + 2] * D + sub * 4);
            if (lr + 3 < rem) s3 = *reinterpret_cast<const float4*>(emb + (size_t)order[q + 3] * D + sub * 4);
            if (lr + 0 < rem) *reinterpret_cast<float4*>(stage + (lr + 0) * D + ((sub ^ ((lr + 0) & 7)) << 2)) = s0;
            if (lr + 1 < rem) *reinterpret_cast<float4*>(stage + (lr + 1) * D + ((sub ^ ((lr + 1) & 7)) << 2)) = s1;
            if (lr + 2 < rem) *reinterpret_cast<float4*>(stage + (lr + 2) * D + ((sub ^ ((lr + 2) & 7)) << 2)) = s2;
            if (lr + 3 < rem) *reinterpret_cast<float4*>(stage + (lr + 3) * D + ((sub ^ ((lr + 3) & 7)) << 2)) = s3;
        }
        __syncthreads();
        if (rloc < rem) {
            const float* srow = stage + rloc * D;
            const int sw = rloc & 7;
            const float4 x0 = *reinterpret_cast<const float4*>(srow + (((sub8 * 4 + 0) ^ sw) << 2));
            const float4 x1 = *reinterpret_cast<const float4*>(srow + (((sub8 * 4 + 1) ^ sw) << 2));
            const float4 x2 = *reinterpret_cast<const float4*>(srow + (((sub8 * 4 + 2) ^ sw) << 2));
            const float4 x3 = *reinterpret_cast<const float4*>(srow + (((sub8 * 4 + 3) ^ sw) << 2));
            float dx, dy, dz, dw;
            dx = x0.x - m0.x; dy = x0.y - m0.y; dz = x0.z - m0.z; dw = x0.w - m0.w;
            float p = dx * dx + dy * dy + dz * dz + dw * dw;
            dx = x1.x - m1.x; dy = x1.y - m1.y; dz = x1.z - m1.z; dw = x1.w - m1.w;
            p += dx * dx + dy * dy + dz * dz + dw * dw;
            dx = x2.x - m2.x; dy = x2.y - m2.y; dz = x2.z - m2.z; dw = x2.w - m2.w;
            p += dx * dx + dy * dy + dz * dz + dw * dw;
            dx = x3.x - m3.x; dy = x3.y - m3.y; dz = x3.z - m3.z; dw = x3.w - m3.w;
            p += dx * dx + dy * dy + dz * dz + dw * dw;
            p += __shfl_xor(p, 1);
            p += __shfl_xor(p, 2);
            p += __shfl_xor(p, 4);
            if (sub8 == 0) local += sqrtf(p);
        }
        __syncthreads();
    }

    // class-level reduce of per-thread sqrt sums (nonzero only at t%8==0)
    local += __shfl_xor(local, 8);
    local += __shfl_xor(local, 16);
    local += __shfl_xor(local, 32);
    if (lane == 0) nacc[w] = local;
    __syncthreads();
    if (t == 0) {
        float tot = 0.f;
        #pragma unroll
        for (int k = 0; k < 8; ++k) tot += nacc[k];
        percls[c] = (cnt > 0) ? tot / (float)cnt : 0.f;
    }
}

// Phase 5: final scalar = sum of per-class means of norms.
__global__ __launch_bounds__(256)
void k_final(const float* __restrict__ percls, float* __restrict__ out) {
    __shared__ float red[256];
    float acc = 0.f;
    for (int c = threadIdx.x; c < C; c += 256) acc += percls[c];
    red[threadIdx.x] = acc;
    __syncthreads();
    for (int s = 128; s > 0; s >>= 1) {
        if (threadIdx.x < s) red[threadIdx.x] += red[threadIdx.x + s];
        __syncthreads();
    }
    if (threadIdx.x == 0) out[0] = red[0];
}

extern "C" void kernel_launch(void* const* d_in, const int* in_sizes, int n_in,
                              void* d_out, int out_size, void* d_ws, size_t ws_size,
                              hipStream_t stream) {
    const float* emb = (const float*)d_in[0];
    const int*   tgt = (const int*)d_in[1];
    const int N = in_sizes[1];

    char* ws = (char*)d_ws;
    unsigned* counts = (unsigned*)(ws);            // C*PAD u32 (zeroed)
    int*      off    = (int*)(ws + 65536);         // C ints
    float*    percls = (float*)(ws + 73728);       // C f32
    int*      cursor = (int*)(ws + 131072);        // C*PAD ints
    int*      order  = (int*)(ws + 262144);        // N ints = 2 MB

    hipMemsetAsync(d_ws, 0, 65536, stream);        // counts only

    k_hist<<<256, 1024, 0, stream>>>(tgt, counts, N);
    k_scan<<<1, 1024, 0, stream>>>(counts, off, cursor);
    k_scatter<<<(N + 255) / 256, 256, 0, stream>>>(tgt, cursor, order, N);
    k_fused<<<C, 512, 0, stream>>>(emb, order, off, counts, percls);
    k_final<<<1, 256, 0, stream>>>(percls, (float*)d_out);
}

// Round 9
// 134.813 us; speedup vs baseline: 1.4148x; 1.1200x over previous
//
#include <hip/hip_runtime.h>
#include <hip/hip_bf16.h>

#define C 1000
#define D 128
#define PAD 16            // one atomic target per 64B line

// Phase 1: histogram of target classes (LDS u32 atomics -> native ds_add).
__global__ __launch_bounds__(1024)
void k_hist(const int* __restrict__ tgt, unsigned* __restrict__ counts, int N) {
    __shared__ unsigned lh[C];
    const int t = threadIdx.x;
    if (t < C) lh[t] = 0u;
    __syncthreads();
    for (int i = blockIdx.x * 1024 + t; i < N; i += gridDim.x * 1024)
        atomicAdd(&lh[tgt[i]], 1u);
    __syncthreads();
    if (t < C) atomicAdd(&counts[t * PAD], lh[t]);
}

// Phase 2: exclusive scan over 1000 counts -> offsets + scatter cursors.
__global__ __launch_bounds__(1024)
void k_scan(const unsigned* __restrict__ counts, int* __restrict__ off,
            int* __restrict__ cursor) {
    __shared__ unsigned a[1024];
    const int t = threadIdx.x;
    const unsigned mine = (t < C) ? counts[t * PAD] : 0u;
    a[t] = mine;
    for (int o = 1; o < 1024; o <<= 1) {
        __syncthreads();
        const unsigned v = (t >= o) ? a[t - o] : 0u;
        __syncthreads();
        a[t] += v;
    }
    __syncthreads();
    if (t < C) {
        const unsigned excl = a[t] - mine;
        off[t] = (int)excl;
        cursor[t * PAD] = (int)excl;
    }
}

// Phase 3: scatter row indices into class-grouped order[].
__global__ __launch_bounds__(256)
void k_scatter(const int* __restrict__ tgt, int* __restrict__ cursor,
               int* __restrict__ order, int N) {
    const int i = blockIdx.x * 256 + threadIdx.x;
    if (i >= N) return;
    const int c = tgt[i];
    const int pos = atomicAdd(&cursor[c * PAD], 1);
    order[pos] = i;
}

// Phase 4 (fused): one block per class.
//   A: sum rows (half-wave = one 512B row, 8 rows in flight) -> mean in LDS.
//   B: free-running re-gather of the same rows (L2/LLC-hot: round-8 FETCH
//      proved the second read is cache-absorbed), 4 independent rows with
//      interleaved shfl reduce chains per half-wave.
__global__ __launch_bounds__(512)
void k_fused(const float* __restrict__ emb, const int* __restrict__ order,
             const int* __restrict__ off, const unsigned* __restrict__ counts,
             float* __restrict__ percls) {
    __shared__ float part[8][D];
    __shared__ float mean_l[D];
    __shared__ float nacc[16];
    const int c    = blockIdx.x;
    const int t    = threadIdx.x;
    const int w    = t >> 6;            // wave 0..7
    const int lane = t & 63;
    const int half = lane >> 5;
    const int sub  = lane & 31;         // float4 column group 0..31
    const int hw   = t >> 5;            // half-wave 0..15
    const int start = off[c];
    const int cnt   = (int)counts[c * PAD];

    // ---- pass A: class sum, 8 rows in flight per half-wave ----
    const int chunkA = (cnt + 7) >> 3;
    const int wsrt   = start + w * chunkA;
    const int wend   = min(start + cnt, wsrt + chunkA);
    float ax = 0.f, ay = 0.f, az = 0.f, aw = 0.f;
    int pos = wsrt + half;
    for (; pos + 14 < wend; pos += 16) {
        const int r0 = order[pos];      const int r1 = order[pos + 2];
        const int r2 = order[pos + 4];  const int r3 = order[pos + 6];
        const int r4 = order[pos + 8];  const int r5 = order[pos + 10];
        const int r6 = order[pos + 12]; const int r7 = order[pos + 14];
        const float4 v0 = *reinterpret_cast<const float4*>(emb + (size_t)r0 * D + sub * 4);
        const float4 v1 = *reinterpret_cast<const float4*>(emb + (size_t)r1 * D + sub * 4);
        const float4 v2 = *reinterpret_cast<const float4*>(emb + (size_t)r2 * D + sub * 4);
        const float4 v3 = *reinterpret_cast<const float4*>(emb + (size_t)r3 * D + sub * 4);
        const float4 v4 = *reinterpret_cast<const float4*>(emb + (size_t)r4 * D + sub * 4);
        const float4 v5 = *reinterpret_cast<const float4*>(emb + (size_t)r5 * D + sub * 4);
        const float4 v6 = *reinterpret_cast<const float4*>(emb + (size_t)r6 * D + sub * 4);
        const float4 v7 = *reinterpret_cast<const float4*>(emb + (size_t)r7 * D + sub * 4);
        ax += (v0.x + v1.x) + (v2.x + v3.x) + (v4.x + v5.x) + (v6.x + v7.x);
        ay += (v0.y + v1.y) + (v2.y + v3.y) + (v4.y + v5.y) + (v6.y + v7.y);
        az += (v0.z + v1.z) + (v2.z + v3.z) + (v4.z + v5.z) + (v6.z + v7.z);
        aw += (v0.w + v1.w) + (v2.w + v3.w) + (v4.w + v5.w) + (v6.w + v7.w);
    }
    for (; pos < wend; pos += 2) {
        const int r0 = order[pos];
        const float4 v0 = *reinterpret_cast<const float4*>(emb + (size_t)r0 * D + sub * 4);
        ax += v0.x; ay += v0.y; az += v0.z; aw += v0.w;
    }
    ax += __shfl_xor(ax, 32);
    ay += __shfl_xor(ay, 32);
    az += __shfl_xor(az, 32);
    aw += __shfl_xor(aw, 32);
    if (half == 0) {
        part[w][sub * 4 + 0] = ax;
        part[w][sub * 4 + 1] = ay;
        part[w][sub * 4 + 2] = az;
        part[w][sub * 4 + 3] = aw;
    }
    __syncthreads();
    if (t < D) {
        float s = 0.f;
        #pragma unroll
        for (int k = 0; k < 8; ++k) s += part[k][t];
        mean_l[t] = s / fmaxf((float)cnt, 1.f);
    }
    __syncthreads();

    // ---- pass B: 4 rows in flight, 4 interleaved shfl chains ----
    const float4 m = *reinterpret_cast<const float4*>(mean_l + sub * 4);
    const int end = start + cnt;
    float local = 0.f;
    int q = start + hw;
    for (; q + 48 < end; q += 64) {
        const int r0 = order[q];
        const int r1 = order[q + 16];
        const int r2 = order[q + 32];
        const int r3 = order[q + 48];
        const float4 v0 = *reinterpret_cast<const float4*>(emb + (size_t)r0 * D + sub * 4);
        const float4 v1 = *reinterpret_cast<const float4*>(emb + (size_t)r1 * D + sub * 4);
        const float4 v2 = *reinterpret_cast<const float4*>(emb + (size_t)r2 * D + sub * 4);
        const float4 v3 = *reinterpret_cast<const float4*>(emb + (size_t)r3 * D + sub * 4);
        float dx, dy, dz, dw;
        dx = v0.x - m.x; dy = v0.y - m.y; dz = v0.z - m.z; dw = v0.w - m.w;
        float p0 = dx * dx + dy * dy + dz * dz + dw * dw;
        dx = v1.x - m.x; dy = v1.y - m.y; dz = v1.z - m.z; dw = v1.w - m.w;
        float p1 = dx * dx + dy * dy + dz * dz + dw * dw;
        dx = v2.x - m.x; dy = v2.y - m.y; dz = v2.z - m.z; dw = v2.w - m.w;
        float p2 = dx * dx + dy * dy + dz * dz + dw * dw;
        dx = v3.x - m.x; dy = v3.y - m.y; dz = v3.z - m.z; dw = v3.w - m.w;
        float p3 = dx * dx + dy * dy + dz * dz + dw * dw;
        p0 += __shfl_xor(p0, 1);  p1 += __shfl_xor(p1, 1);  p2 += __shfl_xor(p2, 1);  p3 += __shfl_xor(p3, 1);
        p0 += __shfl_xor(p0, 2);  p1 += __shfl_xor(p1, 2);  p2 += __shfl_xor(p2, 2);  p3 += __shfl_xor(p3, 2);
        p0 += __shfl_xor(p0, 4);  p1 += __shfl_xor(p1, 4);  p2 += __shfl_xor(p2, 4);  p3 += __shfl_xor(p3, 4);
        p0 += __shfl_xor(p0, 8);  p1 += __shfl_xor(p1, 8);  p2 += __shfl_xor(p2, 8);  p3 += __shfl_xor(p3, 8);
        p0 += __shfl_xor(p0, 16); p1 += __shfl_xor(p1, 16); p2 += __shfl_xor(p2, 16); p3 += __shfl_xor(p3, 16);
        if (sub == 0) local += (sqrtf(p0) + sqrtf(p1)) + (sqrtf(p2) + sqrtf(p3));
    }
    for (; q < end; q += 16) {
        const int r0 = order[q];
        const float4 v0 = *reinterpret_cast<const float4*>(emb + (size_t)r0 * D + sub * 4);
        const float dx = v0.x - m.x, dy = v0.y - m.y, dz = v0.z - m.z, dw = v0.w - m.w;
        float p0 = dx * dx + dy * dy + dz * dz + dw * dw;
        p0 += __shfl_xor(p0, 1);
        p0 += __shfl_xor(p0, 2);
        p0 += __shfl_xor(p0, 4);
        p0 += __shfl_xor(p0, 8);
        p0 += __shfl_xor(p0, 16);
        if (sub == 0) local += sqrtf(p0);
    }
    if (sub == 0) nacc[hw] = local;
    __syncthreads();
    if (t == 0) {
        float tot = 0.f;
        #pragma unroll
        for (int k = 0; k < 16; ++k) tot += nacc[k];
        percls[c] = (cnt > 0) ? tot / (float)cnt : 0.f;
    }
}

// Phase 5: final scalar = sum of per-class means of norms.
__global__ __launch_bounds__(256)
void k_final(const float* __restrict__ percls, float* __restrict__ out) {
    __shared__ float red[256];
    float acc = 0.f;
    for (int c = threadIdx.x; c < C; c += 256) acc += percls[c];
    red[threadIdx.x] = acc;
    __syncthreads();
    for (int s = 128; s > 0; s >>= 1) {
        if (threadIdx.x < s) red[threadIdx.x] += red[threadIdx.x + s];
        __syncthreads();
    }
    if (threadIdx.x == 0) out[0] = red[0];
}

extern "C" void kernel_launch(void* const* d_in, const int* in_sizes, int n_in,
                              void* d_out, int out_size, void* d_ws, size_t ws_size,
                              hipStream_t stream) {
    const float* emb = (const float*)d_in[0];
    const int*   tgt = (const int*)d_in[1];
    const int N = in_sizes[1];

    char* ws = (char*)d_ws;
    unsigned* counts = (unsigned*)(ws);            // C*PAD u32 (zeroed)
    int*      off    = (int*)(ws + 65536);         // C ints
    float*    percls = (float*)(ws + 73728);       // C f32
    int*      cursor = (int*)(ws + 131072);        // C*PAD ints
    int*      order  = (int*)(ws + 262144);        // N ints = 2 MB

    hipMemsetAsync(d_ws, 0, 65536, stream);        // counts only

    k_hist<<<256, 1024, 0, stream>>>(tgt, counts, N);
    k_scan<<<1, 1024, 0, stream>>>(counts, off, cursor);
    k_scatter<<<(N + 255) / 256, 256, 0, stream>>>(tgt, cursor, order, N);
    k_fused<<<C, 512, 0, stream>>>(emb, order, off, counts, percls);
    k_final<<<1, 256, 0, stream>>>(percls, (float*)d_out);
}